// Round 3
// baseline (353.954 us; speedup 1.0000x reference)
//
#include <hip/hip_runtime.h>

// ---------------- constants ----------------
#define B_     16
#define WDIM   512
#define CIN_   512
#define COUT_  512
#define HH     64
#define KC     32           // channels per K-chunk
#define NCHUNK (CIN_/KC)    // 16
#define AFFINE_WG 0.044194173824159216f   // 1/sqrt(512)
#define GAIN_  1.4142135623730951f
#define CLAMP_ 256.0f

// conv LDS geometry (per buffer): W 36864 B + X 10*66*32*2 = 42240 B
#define WBYTES 36864
#define XBYTES 42240
#define BUFBYTES (WBYTES + XBYTES)      // 79104
// double-buffered: 158208 B total

typedef __attribute__((ext_vector_type(4))) float f32x4;
typedef __attribute__((ext_vector_type(8))) short bf16x8;
typedef __attribute__((ext_vector_type(8))) unsigned short u16x8;

__device__ __forceinline__ unsigned short f2bf(float f) {
    union { float f; unsigned u; } un; un.f = f;
    unsigned u = un.u;
    u += 0x7FFFu + ((u >> 16) & 1u);   // round-to-nearest-even
    return (unsigned short)(u >> 16);
}

__device__ __forceinline__ void gl_lds16(const void* g, void* l) {
    __builtin_amdgcn_global_load_lds(
        reinterpret_cast<const __attribute__((address_space(1))) unsigned int*>(
            reinterpret_cast<uintptr_t>(g)),
        reinterpret_cast<__attribute__((address_space(3))) unsigned int*>(
            reinterpret_cast<uintptr_t>(l)),
        16, 0, 0);
}

// ---------------- small setup kernels ----------------

// s[b,c] = w[b,:] . aw[c,:] * AFFINE_WG + ab[c]; partial sums of s^2 per block
__global__ void k_affine(const float* __restrict__ w, const float* __restrict__ aw,
                         const float* __restrict__ ab, float* __restrict__ s,
                         float* __restrict__ part) {
    const int tid = threadIdx.x;
    const int b = blockIdx.x >> 1;
    const int c = ((blockIdx.x & 1) << 8) + tid;
    const f32x4* wr = (const f32x4*)(w + (size_t)b * WDIM);
    const f32x4* ar = (const f32x4*)(aw + (size_t)c * WDIM);
    float acc = 0.f;
    #pragma unroll 4
    for (int k = 0; k < WDIM / 4; ++k) {
        f32x4 a = ar[k], bb = wr[k];
        acc += a[0]*bb[0] + a[1]*bb[1] + a[2]*bb[2] + a[3]*bb[3];
    }
    float sv = acc * AFFINE_WG + ab[c];
    s[b * CIN_ + c] = sv;
    __shared__ float red[256];
    red[tid] = sv * sv;
    __syncthreads();
    for (int off = 128; off > 0; off >>= 1) {
        if (tid < off) red[tid] += red[tid + off];
        __syncthreads();
    }
    if (tid == 0) part[blockIdx.x] = red[0];
}

// alpha[o] = rsqrt(mean over (c,i,j) of cw^2); Q[o,c] = alpha^2 * sum_ij cw^2
__global__ void k_wnorm(const float* __restrict__ cw, float* __restrict__ alpha,
                        float* __restrict__ Q) {
    const int o = blockIdx.x;
    const int tid = threadIdx.x;
    __shared__ float qsh[512];
    __shared__ float red[256];
    __shared__ float a_sh;
    float tot = 0.f;
    #pragma unroll
    for (int half = 0; half < 2; ++half) {
        const int c = tid + half * 256;
        const float* p = cw + ((size_t)o * 512 + c) * 9;
        float qs = 0.f;
        #pragma unroll
        for (int t = 0; t < 9; ++t) { float v = p[t]; qs += v * v; }
        qsh[c] = qs; tot += qs;
    }
    red[tid] = tot; __syncthreads();
    for (int off = 128; off > 0; off >>= 1) {
        if (tid < off) red[tid] += red[tid + off];
        __syncthreads();
    }
    if (tid == 0) { a_sh = rsqrtf(red[0] * (1.0f / 4608.0f)); alpha[o] = a_sh; }
    __syncthreads();
    const float a2 = a_sh * a_sh;
    Q[(size_t)o * 512 + tid]       = a2 * qsh[tid];
    Q[(size_t)o * 512 + tid + 256] = a2 * qsh[tid + 256];
}

// g[b,o] = alpha[o] * rsqrt(rs^2 * sum_c s^2*Q + 1e-8) * rsqrt(ema)
__global__ void k_g(const float* __restrict__ s, const float* __restrict__ part,
                    const float* __restrict__ Q, const float* __restrict__ alpha,
                    const float* __restrict__ ema, float* __restrict__ g) {
    const int tid = threadIdx.x;
    const int b = blockIdx.x >> 1;
    const int o = ((blockIdx.x & 1) << 8) + tid;
    __shared__ float rs2_sh;
    if (tid == 0) {
        float t = 0.f;
        #pragma unroll
        for (int i = 0; i < 32; ++i) t += part[i];
        rs2_sh = 8192.0f / t;          // rs^2
    }
    __syncthreads();
    const f32x4* sh = (const f32x4*)(s + (size_t)b * CIN_);
    const f32x4* qq = (const f32x4*)(Q + (size_t)o * CIN_);
    float d = 0.f;
    #pragma unroll 4
    for (int k = 0; k < CIN_ / 4; ++k) {
        f32x4 a = sh[k], q4 = qq[k];
        d += a[0]*a[0]*q4[0] + a[1]*a[1]*q4[1] + a[2]*a[2]*q4[2] + a[3]*a[3]*q4[3];
    }
    const float ig = rsqrtf(ema[0]);
    g[b * COUT_ + o] = alpha[o] * rsqrtf(d * rs2_sh + 1e-8f) * ig;
}

// conv_weight fp32 -> bf16, pre-swizzled LDS image. One thread = one 16B slot.
// slot byte addr a within a 36864B (ot,cc) block: tap=a>>12, o=(a>>6)&63,
// c0=(((a&63)^((o&6)<<3)))>>1 ; elements j=0..7 land at a+2j (verified identity).
__global__ void k_wprep2(const float* __restrict__ cw, unsigned short* __restrict__ wb) {
    const int S = blockIdx.x * 256 + threadIdx.x;   // grid exactly 294912 slots
    const int p    = S / 2304;                      // ot*16+cc
    const int srem = S - p * 2304;
    const int a    = srem * 16;
    const int tap  = a >> 12;
    const int o    = (a >> 6) & 63;
    const int c0   = ((a & 63) ^ ((o & 6) << 3)) >> 1;
    const int ot = p >> 4, cc = p & 15;
    const int og = ot * 64 + o;
    const int cg = cc * 32 + c0;
    const float* src = cw + ((size_t)og * 512 + cg) * 9 + tap;
    u16x8 v;
    #pragma unroll
    for (int j = 0; j < 8; ++j) v[j] = f2bf(src[j * 9]);
    *(u16x8*)(wb + (size_t)S * 8) = v;
}

// x fp32 [b][c][h][w] -> xbf bf16, scaled by s*rs, channel-interleaved + inverse-swizzled
__global__ void k_xprep(const float* __restrict__ x, const float* __restrict__ s,
                        const float* __restrict__ part, unsigned short* __restrict__ xbf) {
    __shared__ float rs_sh;
    if (threadIdx.x == 0) {
        float t = 0.f;
        #pragma unroll
        for (int i = 0; i < 32; ++i) t += part[i];
        rs_sh = rsqrtf(t * (1.0f / 8192.0f));
    }
    __syncthreads();
    const float rs = rs_sh;
    const int slot = blockIdx.x * 256 + threadIdx.x;   // grid exactly 4194304 slots
    const int pair = slot >> 14;           // b*16+cc
    const int rem  = slot & 16383;
    const int row  = rem >> 8;             // 0..63
    const int ro16 = rem & 255;
    const int full = ro16 * 16 + 64;
    const int col  = full >> 6;            // 1..64 (lds col; img col = col-1)
    const int c0   = ((full & 63) ^ ((col & 6) << 3)) >> 1;   // 0,8,16,24
    const int b    = pair >> 4, cc = pair & 15;
    const int cbase = cc * 32 + c0;
    const float* src = x + (((size_t)(b * CIN_ + cbase)) * HH + row) * HH + (col - 1);
    const float* sp  = s + b * CIN_ + cbase;
    u16x8 v;
    #pragma unroll
    for (int j = 0; j < 8; ++j)
        v[j] = f2bf(src[(size_t)j * 4096] * (sp[j] * rs));
    *(u16x8*)(xbf + (size_t)slot * 8) = v;
}

// zero rows 0 and 65 of the 66x66 output maps (coalesced); cols folded into conv
__global__ void k_border2(float* __restrict__ out) {
    const int f = blockIdx.x * 256 + threadIdx.x;     // grid exactly 1081344
    const int bo = f / 132;
    const int r = f - bo * 132;
    const int row = (r >= 66) ? 65 : 0;
    const int col = (r >= 66) ? (r - 66) : r;
    out[(size_t)bo * 4356 + row * 66 + col] = 0.f;
}

// ---------------- main conv kernel ----------------
// block: 512 threads = 8 waves; 64 out-channels x 8 output rows; wave = 1 row.
// double-buffered LDS, prefetch-next-chunk before compute (T3 2-phase counted).
__global__ __launch_bounds__(512, 2) void k_conv3(
    const unsigned short* __restrict__ xbf, const unsigned short* __restrict__ wb,
    const float* __restrict__ g, const float* __restrict__ bias,
    float* __restrict__ out) {
    __shared__ char lds[2 * BUFBYTES];   // 158208 B

    const int tid  = threadIdx.x;
    const int lane = tid & 63;
    const int wv   = tid >> 6;       // wave id 0..7 -> output row h0+wv
    const int l15  = lane & 15;
    const int hi   = lane >> 4;      // 0..3
    const int b  = blockIdx.z;
    const int ot = blockIdx.y;
    const int rt = blockIdx.x;
    const int h0 = rt * 8;

    const f32x4 zero4 = {0.f, 0.f, 0.f, 0.f};
    f32x4 acc[4][4];
    #pragma unroll
    for (int i = 0; i < 4; ++i)
        #pragma unroll
        for (int j = 0; j < 4; ++j) acc[i][j] = zero4;

    // zero both X buffers once (pad cols 0/65 + possible OOB halo rows)
    {
        unsigned int* x0 = (unsigned int*)(lds + WBYTES);
        unsigned int* x1 = (unsigned int*)(lds + BUFBYTES + WBYTES);
        for (int i = tid; i < XBYTES / 4; i += 512) { x0[i] = 0u; x1[i] = 0u; }
    }
    __syncthreads();

    const char* wsrc0 = (const char*)wb + (size_t)ot * 16 * WBYTES;
    const char* xsrc0 = (const char*)xbf + (size_t)b * 16 * 262144;   // 64*4096 per (b,cc)

    // stage chunk cc into buffer base: waves 0-3 -> W, waves 4-7 -> X
    auto STAGE = [&](int cc, char* base) {
        if (tid < 256) {
            const char* wsrc = wsrc0 + (size_t)cc * WBYTES;
            #pragma unroll
            for (int r = 0; r < 9; ++r)
                gl_lds16(wsrc + r * 4096 + tid * 16, base + r * 4096 + tid * 16);
        } else {
            const int t2 = tid - 256;
            const char* xsrc = xsrc0 + (size_t)cc * 262144;
            char* xb = base + WBYTES;
            #pragma unroll
            for (int r = 0; r < 10; ++r) {
                const int h_in = h0 - 1 + r;
                if ((unsigned)h_in < 64u)
                    gl_lds16(xsrc + (size_t)h_in * 4096 + t2 * 16,
                             xb + r * 4224 + 64 + t2 * 16);
            }
        }
    };

    STAGE(0, lds);
    __syncthreads();                 // drains vmcnt -> buf0 ready
    int cur = 0;

    for (int cc = 0; cc < NCHUNK; ++cc) {
        char* cbase = lds + cur * BUFBYTES;
        if (cc + 1 < NCHUNK) STAGE(cc + 1, lds + (cur ^ 1) * BUFBYTES);

        const char* Wl = cbase;
        const char* Xl = cbase + WBYTES;
        #pragma unroll
        for (int tap = 0; tap < 9; ++tap) {
            const int ti = tap / 3, tj = tap - ti * 3;
            bf16x8 af[4];
            #pragma unroll
            for (int mi = 0; mi < 4; ++mi) {
                const int o = mi * 16 + l15;
                int byte = (tap << 12) + (o << 6) + (hi << 4);
                byte ^= ((o & 6) << 3);
                af[mi] = *(const bf16x8*)(Wl + byte);
            }
            bf16x8 bg[4];
            const int row = wv + ti;
            #pragma unroll
            for (int ni = 0; ni < 4; ++ni) {
                const int col = ni * 16 + l15 + tj;
                int byte = (((row * 66 + col) << 5) + (hi << 3)) << 1;
                byte ^= ((col & 6) << 3);
                bg[ni] = *(const bf16x8*)(Xl + byte);
            }
            #pragma unroll
            for (int mi = 0; mi < 4; ++mi)
                #pragma unroll
                for (int ni = 0; ni < 4; ++ni)
                    acc[mi][ni] = __builtin_amdgcn_mfma_f32_16x16x32_bf16(
                        af[mi], bg[ni], acc[mi][ni], 0, 0, 0);
        }
        __syncthreads();             // drains this wave's prefetch; buf swap safe
        cur ^= 1;
    }

    // ---- epilogue: *G, +bias, lrelu*gain, clamp, store interior + col borders ----
    {
        const int obase = ot * 64;
        const int orow = h0 + wv + 1;
        #pragma unroll
        for (int mi = 0; mi < 4; ++mi) {
            #pragma unroll
            for (int r = 0; r < 4; ++r) {
                const int o = obase + mi * 16 + hi * 4 + r;
                const float gg = g[b * COUT_ + o];
                const float bb = bias[o];
                float* op = out + ((size_t)(b * COUT_ + o) * 66 + orow) * 66;
                #pragma unroll
                for (int ni = 0; ni < 4; ++ni) {
                    float v = acc[mi][ni][r] * gg + bb;
                    v = (v >= 0.f ? v : v * 0.2f) * GAIN_;
                    v = fminf(fmaxf(v, -CLAMP_), CLAMP_);
                    op[ni * 16 + l15 + 1] = v;
                }
                if (l15 == 0)  op[0]  = 0.f;
                if (l15 == 15) op[65] = 0.f;
            }
        }
    }
}

// ---------------- launcher ----------------
extern "C" void kernel_launch(void* const* d_in, const int* in_sizes, int n_in,
                              void* d_out, int out_size, void* d_ws, size_t ws_size,
                              hipStream_t stream) {
    const float* x    = (const float*)d_in[0];
    const float* w    = (const float*)d_in[1];
    const float* aw   = (const float*)d_in[2];
    const float* ab   = (const float*)d_in[3];
    const float* cw   = (const float*)d_in[4];
    const float* bias = (const float*)d_in[5];
    const float* ema  = (const float*)d_in[6];
    float* out = (float*)d_out;

    float* wsf   = (float*)d_ws;
    float* s     = wsf;                 // 8192
    float* part  = wsf + 8192;          // 32
    float* alpha = wsf + 16512;         // 512
    float* Q     = wsf + 17024;         // 262144
    float* g     = wsf + 279168;        // 8192
    unsigned short* wb  = (unsigned short*)((char*)d_ws + 1179648);  // 4718592 B
    unsigned short* xbf = (unsigned short*)((char*)d_ws + 5898240);  // 67108864 B

    k_affine <<<32, 256, 0, stream>>>(w, aw, ab, s, part);
    k_wnorm  <<<512, 256, 0, stream>>>(cw, alpha, Q);
    k_g      <<<32, 256, 0, stream>>>(s, part, Q, alpha, ema, g);
    k_wprep2 <<<1152, 256, 0, stream>>>(cw, wb);
    k_xprep  <<<16384, 256, 0, stream>>>(x, s, part, xbf);
    k_border2<<<4224, 256, 0, stream>>>(out);
    k_conv3  <<<dim3(8, 8, 16), 512, 0, stream>>>(xbf, wb, g, bias, out);
}

// Round 4
// 342.064 us; speedup vs baseline: 1.0348x; 1.0348x over previous
//
#include <hip/hip_runtime.h>

// ---------------- constants ----------------
#define B_     16
#define WDIM   512
#define CIN_   512
#define COUT_  512
#define HH     64
#define KC     32           // channels per K-chunk
#define NCHUNK (CIN_/KC)    // 16
#define AFFINE_WG 0.044194173824159216f   // 1/sqrt(512)
#define GAIN_  1.4142135623730951f
#define CLAMP_ 256.0f

// conv LDS geometry (per buffer): W 36864 B + X 10*66*32*2 = 42240 B
#define WBYTES 36864
#define XBYTES 42240

typedef __attribute__((ext_vector_type(4))) float f32x4;
typedef __attribute__((ext_vector_type(8))) short bf16x8;
typedef __attribute__((ext_vector_type(8))) unsigned short u16x8;

__device__ __forceinline__ unsigned short f2bf(float f) {
    union { float f; unsigned u; } un; un.f = f;
    unsigned u = un.u;
    u += 0x7FFFu + ((u >> 16) & 1u);   // round-to-nearest-even
    return (unsigned short)(u >> 16);
}

__device__ __forceinline__ void gl_lds16(const void* g, void* l) {
    __builtin_amdgcn_global_load_lds(
        reinterpret_cast<const __attribute__((address_space(1))) unsigned int*>(
            reinterpret_cast<uintptr_t>(g)),
        reinterpret_cast<__attribute__((address_space(3))) unsigned int*>(
            reinterpret_cast<uintptr_t>(l)),
        16, 0, 0);
}

// ---------------- small setup kernels ----------------

// s[b,c] = w[b,:] . aw[c,:] * AFFINE_WG + ab[c]; partial sums of s^2 per block
__global__ void k_affine(const float* __restrict__ w, const float* __restrict__ aw,
                         const float* __restrict__ ab, float* __restrict__ s,
                         float* __restrict__ part) {
    const int tid = threadIdx.x;
    const int b = blockIdx.x >> 1;
    const int c = ((blockIdx.x & 1) << 8) + tid;
    const f32x4* wr = (const f32x4*)(w + (size_t)b * WDIM);
    const f32x4* ar = (const f32x4*)(aw + (size_t)c * WDIM);
    float acc = 0.f;
    #pragma unroll 4
    for (int k = 0; k < WDIM / 4; ++k) {
        f32x4 a = ar[k], bb = wr[k];
        acc += a[0]*bb[0] + a[1]*bb[1] + a[2]*bb[2] + a[3]*bb[3];
    }
    float sv = acc * AFFINE_WG + ab[c];
    s[b * CIN_ + c] = sv;
    __shared__ float red[256];
    red[tid] = sv * sv;
    __syncthreads();
    for (int off = 128; off > 0; off >>= 1) {
        if (tid < off) red[tid] += red[tid + off];
        __syncthreads();
    }
    if (tid == 0) part[blockIdx.x] = red[0];
}

// alpha[o] = rsqrt(mean over (c,i,j) of cw^2); Q[o,c] = alpha^2 * sum_ij cw^2
__global__ void k_wnorm(const float* __restrict__ cw, float* __restrict__ alpha,
                        float* __restrict__ Q) {
    const int o = blockIdx.x;
    const int tid = threadIdx.x;
    __shared__ float qsh[512];
    __shared__ float red[256];
    __shared__ float a_sh;
    float tot = 0.f;
    #pragma unroll
    for (int half = 0; half < 2; ++half) {
        const int c = tid + half * 256;
        const float* p = cw + ((size_t)o * 512 + c) * 9;
        float qs = 0.f;
        #pragma unroll
        for (int t = 0; t < 9; ++t) { float v = p[t]; qs += v * v; }
        qsh[c] = qs; tot += qs;
    }
    red[tid] = tot; __syncthreads();
    for (int off = 128; off > 0; off >>= 1) {
        if (tid < off) red[tid] += red[tid + off];
        __syncthreads();
    }
    if (tid == 0) { a_sh = rsqrtf(red[0] * (1.0f / 4608.0f)); alpha[o] = a_sh; }
    __syncthreads();
    const float a2 = a_sh * a_sh;
    Q[(size_t)o * 512 + tid]       = a2 * qsh[tid];
    Q[(size_t)o * 512 + tid + 256] = a2 * qsh[tid + 256];
}

// g[b,o] = alpha[o] * rsqrt(rs^2 * sum_c s^2*Q + 1e-8) * rsqrt(ema)
__global__ void k_g(const float* __restrict__ s, const float* __restrict__ part,
                    const float* __restrict__ Q, const float* __restrict__ alpha,
                    const float* __restrict__ ema, float* __restrict__ g) {
    const int tid = threadIdx.x;
    const int b = blockIdx.x >> 1;
    const int o = ((blockIdx.x & 1) << 8) + tid;
    __shared__ float rs2_sh;
    if (tid == 0) {
        float t = 0.f;
        #pragma unroll
        for (int i = 0; i < 32; ++i) t += part[i];
        rs2_sh = 8192.0f / t;          // rs^2
    }
    __syncthreads();
    const f32x4* sh = (const f32x4*)(s + (size_t)b * CIN_);
    const f32x4* qq = (const f32x4*)(Q + (size_t)o * CIN_);
    float d = 0.f;
    #pragma unroll 4
    for (int k = 0; k < CIN_ / 4; ++k) {
        f32x4 a = sh[k], q4 = qq[k];
        d += a[0]*a[0]*q4[0] + a[1]*a[1]*q4[1] + a[2]*a[2]*q4[2] + a[3]*a[3]*q4[3];
    }
    const float ig = rsqrtf(ema[0]);
    g[b * COUT_ + o] = alpha[o] * rsqrtf(d * rs2_sh + 1e-8f) * ig;
}

// conv_weight fp32 -> bf16, pre-swizzled LDS image. One thread = one 16B slot.
__global__ void k_wprep2(const float* __restrict__ cw, unsigned short* __restrict__ wb) {
    const int S = blockIdx.x * 256 + threadIdx.x;   // grid exactly 294912 slots
    const int p    = S / 2304;                      // ot*16+cc
    const int srem = S - p * 2304;
    const int a    = srem * 16;
    const int tap  = a >> 12;
    const int o    = (a >> 6) & 63;
    const int c0   = ((a & 63) ^ ((o & 6) << 3)) >> 1;
    const int ot = p >> 4, cc = p & 15;
    const int og = ot * 64 + o;
    const int cg = cc * 32 + c0;
    const float* src = cw + ((size_t)og * 512 + cg) * 9 + tap;
    u16x8 v;
    #pragma unroll
    for (int j = 0; j < 8; ++j) v[j] = f2bf(src[j * 9]);
    *(u16x8*)(wb + (size_t)S * 8) = v;
}

// x fp32 -> xbf bf16 (scaled, channel-interleaved, inverse-swizzled), LDS-bounce.
// block = (b, cc, rowgroup of 8 rows); coalesced reads AND writes.
__global__ void k_xprep2(const float* __restrict__ x, const float* __restrict__ s,
                         const float* __restrict__ part, unsigned short* __restrict__ xbf) {
    __shared__ float rs_sh;
    __shared__ char tile[8 * 4096];            // 8 rows x 4096B slab rows
    const int tid = threadIdx.x;
    if (tid == 0) {
        float t = 0.f;
        #pragma unroll
        for (int i = 0; i < 32; ++i) t += part[i];
        rs_sh = rsqrtf(t * (1.0f / 8192.0f));
    }
    __syncthreads();
    const float rs = rs_sh;
    const int blk = blockIdx.x;                // grid 16*16*8 = 2048
    const int b  = blk >> 7;
    const int cc = (blk >> 3) & 15;
    const int rg = blk & 7;
    const int c   = tid >> 3;                  // 0..31
    const int k8  = tid & 7;                   // 8-col segment
    const float sc = s[b * CIN_ + cc * 32 + c] * rs;
    const float* src = x + (((size_t)(b * CIN_ + cc * 32 + c)) * HH + rg * 8) * HH + k8 * 8;
    #pragma unroll
    for (int row = 0; row < 8; ++row) {
        const f32x4 v0 = *(const f32x4*)(src + (size_t)row * HH);
        const f32x4 v1 = *(const f32x4*)(src + (size_t)row * HH + 4);
        #pragma unroll
        for (int q = 0; q < 8; ++q) {
            const float v = (q < 4) ? v0[q] : v1[q - 4];
            const int col = k8 * 8 + q + 1;                 // lds col 1..64
            const int byte = ((col * 64 + 2 * c) ^ ((col & 6) << 3)) - 64;
            *(unsigned short*)(tile + row * 4096 + byte) = f2bf(v * sc);
        }
    }
    __syncthreads();
    unsigned short* dst = xbf + ((size_t)(b * 16 + cc) * 64 + rg * 8) * 2048;
    const u16x8* tsrc = (const u16x8*)tile;
    #pragma unroll
    for (int k = 0; k < 8; ++k)
        *(u16x8*)(dst + (size_t)(tid + k * 256) * 8) = tsrc[tid + k * 256];
}

// ---------------- main conv kernel ----------------
// 512 thr = 8 waves; 64 och x 8 rows per block; STATIC double buffers;
// minimum-2-phase: STAGE(other,next) -> COMPUTE(cur) -> barrier.
__global__ __launch_bounds__(512, 1) void k_conv4(
    const unsigned short* __restrict__ xbf, const unsigned short* __restrict__ wb,
    const float* __restrict__ g, const float* __restrict__ bias,
    float* __restrict__ out) {
    __shared__ char bufA[WBYTES + XBYTES];   // 79104 each, statically distinct
    __shared__ char bufB[WBYTES + XBYTES];

    const int tid  = threadIdx.x;
    const int lane = tid & 63;
    const int wv   = tid >> 6;       // wave id 0..7 -> output row h0+wv
    const int l15  = lane & 15;
    const int hi   = lane >> 4;      // 0..3

    // bijective XCD-chunked swizzle: 1024 wgs, 8 XCDs, 128/XCD
    const int orig = blockIdx.x;
    const int wg = (orig & 7) * 128 + (orig >> 3);
    const int b  = wg >> 6;
    const int ot = (wg >> 3) & 7;
    const int rt = wg & 7;
    const int h0 = rt * 8;

    const f32x4 zero4 = {0.f, 0.f, 0.f, 0.f};
    f32x4 acc[4][4];
    #pragma unroll
    for (int i = 0; i < 4; ++i)
        #pragma unroll
        for (int j = 0; j < 4; ++j) acc[i][j] = zero4;

    // zero both X buffers once (pad cols 0/65 + OOB halo rows stay 0)
    {
        unsigned int* x0 = (unsigned int*)(bufA + WBYTES);
        unsigned int* x1 = (unsigned int*)(bufB + WBYTES);
        for (int i = tid; i < XBYTES / 4; i += 512) { x0[i] = 0u; x1[i] = 0u; }
    }
    __syncthreads();

    const char* wsrc0 = (const char*)wb + (size_t)ot * 16 * WBYTES;
    const char* xsrc0 = (const char*)xbf + (size_t)b * 16 * 262144;

    auto STAGE = [&](char* base, int cc) {
        if (tid < 256) {
            const char* wsrc = wsrc0 + (size_t)cc * WBYTES;
            #pragma unroll
            for (int r = 0; r < 9; ++r)
                gl_lds16(wsrc + r * 4096 + tid * 16, base + r * 4096 + tid * 16);
        } else {
            const int t2 = tid - 256;
            const char* xsrc = xsrc0 + (size_t)cc * 262144;
            char* xb = base + WBYTES;
            #pragma unroll
            for (int r = 0; r < 10; ++r) {
                const int h_in = h0 - 1 + r;
                if ((unsigned)h_in < 64u)
                    gl_lds16(xsrc + (size_t)h_in * 4096 + t2 * 16,
                             xb + r * 4224 + 64 + t2 * 16);
            }
        }
    };

    auto COMPUTE = [&](const char* Wl, const char* Xl) {
        #pragma unroll
        for (int tap = 0; tap < 9; ++tap) {
            const int ti = tap / 3, tj = tap - ti * 3;
            bf16x8 af[4];
            #pragma unroll
            for (int mi = 0; mi < 4; ++mi) {
                const int o = mi * 16 + l15;
                int byte = (tap << 12) + (o << 6) + (hi << 4);
                byte ^= ((o & 6) << 3);
                af[mi] = *(const bf16x8*)(Wl + byte);
            }
            bf16x8 bg[4];
            const int row = wv + ti;
            #pragma unroll
            for (int ni = 0; ni < 4; ++ni) {
                const int col = ni * 16 + l15 + tj;
                int byte = (((row * 66 + col) << 5) + (hi << 3)) << 1;
                byte ^= ((col & 6) << 3);
                bg[ni] = *(const bf16x8*)(Xl + byte);
            }
            if (tap == 5) __builtin_amdgcn_s_barrier();   // mid-chunk role split
            __builtin_amdgcn_s_setprio(1);
            #pragma unroll
            for (int mi = 0; mi < 4; ++mi)
                #pragma unroll
                for (int ni = 0; ni < 4; ++ni)
                    acc[mi][ni] = __builtin_amdgcn_mfma_f32_16x16x32_bf16(
                        af[mi], bg[ni], acc[mi][ni], 0, 0, 0);
            __builtin_amdgcn_s_setprio(0);
        }
    };

    STAGE(bufA, 0);
    __syncthreads();                 // buf A ready

    #pragma unroll 1
    for (int it = 0; it < 8; ++it) {
        const int cc = it * 2;
        STAGE(bufB, cc + 1);                       // prefetch into B (static)
        COMPUTE(bufA, bufA + WBYTES);
        __syncthreads();                           // drains B's loads; A reusable
        if (cc + 2 < NCHUNK) STAGE(bufA, cc + 2);  // prefetch into A (static)
        COMPUTE(bufB, bufB + WBYTES);
        __syncthreads();
    }

    // ---- epilogue: *G, +bias, lrelu*gain, clamp, store interior + borders ----
    {
        const int obase = ot * 64;
        const int orow = h0 + wv + 1;
        #pragma unroll
        for (int mi = 0; mi < 4; ++mi) {
            #pragma unroll
            for (int r = 0; r < 4; ++r) {
                const int o = obase + mi * 16 + hi * 4 + r;
                const float gg = g[b * COUT_ + o];
                const float bb = bias[o];
                float* op = out + ((size_t)(b * COUT_ + o) * 66 + orow) * 66;
                #pragma unroll
                for (int ni = 0; ni < 4; ++ni) {
                    float v = acc[mi][ni][r] * gg + bb;
                    v = (v >= 0.f ? v : v * 0.2f) * GAIN_;
                    v = fminf(fmaxf(v, -CLAMP_), CLAMP_);
                    op[ni * 16 + l15 + 1] = v;
                }
                if (l15 == 0)  op[0]  = 0.f;
                if (l15 == 15) op[65] = 0.f;
            }
        }
        // top/bottom border rows for this block's 64 maps
        if (rt == 0 || rt == 7) {
            const int row = (rt == 0) ? 0 : 65;
            for (int i = tid; i < 64 * 66; i += 512) {
                const int o = obase + i / 66, col = i - (i / 66) * 66;
                out[((size_t)(b * COUT_ + o) * 66 + row) * 66 + col] = 0.f;
            }
        }
    }
}

// ---------------- launcher ----------------
extern "C" void kernel_launch(void* const* d_in, const int* in_sizes, int n_in,
                              void* d_out, int out_size, void* d_ws, size_t ws_size,
                              hipStream_t stream) {
    const float* x    = (const float*)d_in[0];
    const float* w    = (const float*)d_in[1];
    const float* aw   = (const float*)d_in[2];
    const float* ab   = (const float*)d_in[3];
    const float* cw   = (const float*)d_in[4];
    const float* bias = (const float*)d_in[5];
    const float* ema  = (const float*)d_in[6];
    float* out = (float*)d_out;

    float* wsf   = (float*)d_ws;
    float* s     = wsf;                 // 8192
    float* part  = wsf + 8192;          // 32
    float* alpha = wsf + 16512;         // 512
    float* Q     = wsf + 17024;         // 262144
    float* g     = wsf + 279168;        // 8192
    unsigned short* wb  = (unsigned short*)((char*)d_ws + 1179648);  // 4718592 B
    unsigned short* xbf = (unsigned short*)((char*)d_ws + 5898240);  // 67108864 B

    k_affine <<<32, 256, 0, stream>>>(w, aw, ab, s, part);
    k_wnorm  <<<512, 256, 0, stream>>>(cw, alpha, Q);
    k_g      <<<32, 256, 0, stream>>>(s, part, Q, alpha, ema, g);
    k_wprep2 <<<1152, 256, 0, stream>>>(cw, wb);
    k_xprep2 <<<2048, 256, 0, stream>>>(x, s, part, xbf);
    k_conv4  <<<1024, 512, 0, stream>>>(xbf, wb, g, bias, out);
}

// Round 5
// 337.650 us; speedup vs baseline: 1.0483x; 1.0131x over previous
//
#include <hip/hip_runtime.h>

// ---------------- constants ----------------
#define B_     16
#define WDIM   512
#define CIN_   512
#define COUT_  512
#define HH     64
#define KC     32           // channels per K-chunk
#define NCHUNK (CIN_/KC)    // 16
#define AFFINE_WG 0.044194173824159216f   // 1/sqrt(512)
#define GAIN_  1.4142135623730951f
#define CLAMP_ 256.0f

// conv LDS geometry: W 36864 B + X 10*66*32*2 = 42240 B (single buffer)
#define WBYTES 36864
#define XBYTES 42240

typedef __attribute__((ext_vector_type(4))) float f32x4;
typedef __attribute__((ext_vector_type(8))) short bf16x8;
typedef __attribute__((ext_vector_type(8))) unsigned short u16x8;

__device__ __forceinline__ unsigned short f2bf(float f) {
    union { float f; unsigned u; } un; un.f = f;
    unsigned u = un.u;
    u += 0x7FFFu + ((u >> 16) & 1u);   // round-to-nearest-even
    return (unsigned short)(u >> 16);
}

__device__ __forceinline__ void gl_lds16(const void* g, void* l) {
    __builtin_amdgcn_global_load_lds(
        reinterpret_cast<const __attribute__((address_space(1))) unsigned int*>(
            reinterpret_cast<uintptr_t>(g)),
        reinterpret_cast<__attribute__((address_space(3))) unsigned int*>(
            reinterpret_cast<uintptr_t>(l)),
        16, 0, 0);
}

// ---------------- small setup kernels ----------------

// s[b,c] = w[b,:] . aw[c,:] * AFFINE_WG + ab[c]; partial sums of s^2 per block
__global__ void k_affine(const float* __restrict__ w, const float* __restrict__ aw,
                         const float* __restrict__ ab, float* __restrict__ s,
                         float* __restrict__ part) {
    const int tid = threadIdx.x;
    const int b = blockIdx.x >> 1;
    const int c = ((blockIdx.x & 1) << 8) + tid;
    const f32x4* wr = (const f32x4*)(w + (size_t)b * WDIM);
    const f32x4* ar = (const f32x4*)(aw + (size_t)c * WDIM);
    float acc = 0.f;
    #pragma unroll 4
    for (int k = 0; k < WDIM / 4; ++k) {
        f32x4 a = ar[k], bb = wr[k];
        acc += a[0]*bb[0] + a[1]*bb[1] + a[2]*bb[2] + a[3]*bb[3];
    }
    float sv = acc * AFFINE_WG + ab[c];
    s[b * CIN_ + c] = sv;
    __shared__ float red[256];
    red[tid] = sv * sv;
    __syncthreads();
    for (int off = 128; off > 0; off >>= 1) {
        if (tid < off) red[tid] += red[tid + off];
        __syncthreads();
    }
    if (tid == 0) part[blockIdx.x] = red[0];
}

// alpha[o] = rsqrt(mean over (c,i,j) of cw^2); Q[o,c] = alpha^2 * sum_ij cw^2
__global__ void k_wnorm(const float* __restrict__ cw, float* __restrict__ alpha,
                        float* __restrict__ Q) {
    const int o = blockIdx.x;
    const int tid = threadIdx.x;
    __shared__ float qsh[512];
    __shared__ float red[256];
    __shared__ float a_sh;
    float tot = 0.f;
    #pragma unroll
    for (int half = 0; half < 2; ++half) {
        const int c = tid + half * 256;
        const float* p = cw + ((size_t)o * 512 + c) * 9;
        float qs = 0.f;
        #pragma unroll
        for (int t = 0; t < 9; ++t) { float v = p[t]; qs += v * v; }
        qsh[c] = qs; tot += qs;
    }
    red[tid] = tot; __syncthreads();
    for (int off = 128; off > 0; off >>= 1) {
        if (tid < off) red[tid] += red[tid + off];
        __syncthreads();
    }
    if (tid == 0) { a_sh = rsqrtf(red[0] * (1.0f / 4608.0f)); alpha[o] = a_sh; }
    __syncthreads();
    const float a2 = a_sh * a_sh;
    Q[(size_t)o * 512 + tid]       = a2 * qsh[tid];
    Q[(size_t)o * 512 + tid + 256] = a2 * qsh[tid + 256];
}

// g[b,o] = alpha[o] * rsqrt(rs^2 * sum_c s^2*Q + 1e-8) * rsqrt(ema)
__global__ void k_g(const float* __restrict__ s, const float* __restrict__ part,
                    const float* __restrict__ Q, const float* __restrict__ alpha,
                    const float* __restrict__ ema, float* __restrict__ g) {
    const int tid = threadIdx.x;
    const int b = blockIdx.x >> 1;
    const int o = ((blockIdx.x & 1) << 8) + tid;
    __shared__ float rs2_sh;
    if (tid == 0) {
        float t = 0.f;
        #pragma unroll
        for (int i = 0; i < 32; ++i) t += part[i];
        rs2_sh = 8192.0f / t;          // rs^2
    }
    __syncthreads();
    const f32x4* sh = (const f32x4*)(s + (size_t)b * CIN_);
    const f32x4* qq = (const f32x4*)(Q + (size_t)o * CIN_);
    float d = 0.f;
    #pragma unroll 4
    for (int k = 0; k < CIN_ / 4; ++k) {
        f32x4 a = sh[k], q4 = qq[k];
        d += a[0]*a[0]*q4[0] + a[1]*a[1]*q4[1] + a[2]*a[2]*q4[2] + a[3]*a[3]*q4[3];
    }
    const float ig = rsqrtf(ema[0]);
    g[b * COUT_ + o] = alpha[o] * rsqrtf(d * rs2_sh + 1e-8f) * ig;
}

// conv_weight fp32 -> bf16, pre-swizzled LDS image. One thread = one 16B slot.
__global__ void k_wprep2(const float* __restrict__ cw, unsigned short* __restrict__ wb) {
    const int S = blockIdx.x * 256 + threadIdx.x;   // grid exactly 294912 slots
    const int p    = S / 2304;                      // ot*16+cc
    const int srem = S - p * 2304;
    const int a    = srem * 16;
    const int tap  = a >> 12;
    const int o    = (a >> 6) & 63;
    const int c0   = ((a & 63) ^ ((o & 6) << 3)) >> 1;
    const int ot = p >> 4, cc = p & 15;
    const int og = ot * 64 + o;
    const int cg = cc * 32 + c0;
    const float* src = cw + ((size_t)og * 512 + cg) * 9 + tap;
    u16x8 v;
    #pragma unroll
    for (int j = 0; j < 8; ++j) v[j] = f2bf(src[j * 9]);
    *(u16x8*)(wb + (size_t)S * 8) = v;
}

// x fp32 -> xbf bf16 (scaled, channel-interleaved, inverse-swizzled), LDS-bounce.
__global__ void k_xprep2(const float* __restrict__ x, const float* __restrict__ s,
                         const float* __restrict__ part, unsigned short* __restrict__ xbf) {
    __shared__ float rs_sh;
    __shared__ char tile[8 * 4096];            // 8 rows x 4096B slab rows
    const int tid = threadIdx.x;
    if (tid == 0) {
        float t = 0.f;
        #pragma unroll
        for (int i = 0; i < 32; ++i) t += part[i];
        rs_sh = rsqrtf(t * (1.0f / 8192.0f));
    }
    __syncthreads();
    const float rs = rs_sh;
    const int blk = blockIdx.x;                // grid 16*16*8 = 2048
    const int b  = blk >> 7;
    const int cc = (blk >> 3) & 15;
    const int rg = blk & 7;
    const int c   = tid >> 3;                  // 0..31
    const int k8  = tid & 7;                   // 8-col segment
    const float sc = s[b * CIN_ + cc * 32 + c] * rs;
    const float* src = x + (((size_t)(b * CIN_ + cc * 32 + c)) * HH + rg * 8) * HH + k8 * 8;
    #pragma unroll
    for (int row = 0; row < 8; ++row) {
        const f32x4 v0 = *(const f32x4*)(src + (size_t)row * HH);
        const f32x4 v1 = *(const f32x4*)(src + (size_t)row * HH + 4);
        #pragma unroll
        for (int q = 0; q < 8; ++q) {
            const float v = (q < 4) ? v0[q] : v1[q - 4];
            const int col = k8 * 8 + q + 1;                 // lds col 1..64
            const int byte = ((col * 64 + 2 * c) ^ ((col & 6) << 3)) - 64;
            *(unsigned short*)(tile + row * 4096 + byte) = f2bf(v * sc);
        }
    }
    __syncthreads();
    unsigned short* dst = xbf + ((size_t)(b * 16 + cc) * 64 + rg * 8) * 2048;
    const u16x8* tsrc = (const u16x8*)tile;
    #pragma unroll
    for (int k = 0; k < 8; ++k)
        *(u16x8*)(dst + (size_t)(tid + k * 256) * 8) = tsrc[tid + k * 256];
}

// ---------------- main conv kernel ----------------
// 256 thr = 4 waves; wave computes 64 och x 2 rows x 64 cols (acc[2][4][4]);
// block = 64 och x 8 rows; single-buffer, 2 blocks/CU for cross-block overlap.
__global__ __launch_bounds__(256, 2) void k_conv5(
    const unsigned short* __restrict__ xbf, const unsigned short* __restrict__ wb,
    const float* __restrict__ g, const float* __restrict__ bias,
    float* __restrict__ out) {
    __shared__ char Wl[WBYTES];
    __shared__ char Xl[XBYTES];

    const int tid  = threadIdx.x;
    const int lane = tid & 63;
    const int wv   = tid >> 6;       // wave id 0..3 -> output rows h0+2wv, h0+2wv+1
    const int l15  = lane & 15;
    const int hi   = lane >> 4;      // 0..3

    // bijective XCD-chunked swizzle: 1024 wgs, 8 XCDs, 128/XCD
    const int orig = blockIdx.x;
    const int wg = (orig & 7) * 128 + (orig >> 3);
    const int b  = wg >> 6;
    const int ot = (wg >> 3) & 7;
    const int rt = wg & 7;
    const int h0 = rt * 8;

    const f32x4 zero4 = {0.f, 0.f, 0.f, 0.f};
    f32x4 acc[2][4][4];
    #pragma unroll
    for (int rr = 0; rr < 2; ++rr)
        #pragma unroll
        for (int i = 0; i < 4; ++i)
            #pragma unroll
            for (int j = 0; j < 4; ++j) acc[rr][i][j] = zero4;

    // zero X buffer once (pad cols 0/65 + OOB halo rows stay 0 across chunks)
    {
        unsigned int* x0 = (unsigned int*)Xl;
        for (int i = tid; i < XBYTES / 4; i += 256) x0[i] = 0u;
    }
    __syncthreads();

    const char* wsrc0 = (const char*)wb + (size_t)ot * 16 * WBYTES;
    const char* xsrc0 = (const char*)xbf + (size_t)b * 16 * 262144;

    #pragma unroll 1
    for (int cc = 0; cc < NCHUNK; ++cc) {
        // ---- stage: 9 W slabs + up to 10 X row slabs, all linear 16B/lane ----
        {
            const char* wsrc = wsrc0 + (size_t)cc * WBYTES;
            #pragma unroll
            for (int r = 0; r < 9; ++r)
                gl_lds16(wsrc + r * 4096 + tid * 16, Wl + r * 4096 + tid * 16);
            const char* xsrc = xsrc0 + (size_t)cc * 262144;
            #pragma unroll
            for (int r = 0; r < 10; ++r) {
                const int h_in = h0 - 1 + r;
                if ((unsigned)h_in < 64u)
                    gl_lds16(xsrc + (size_t)h_in * 4096 + tid * 16,
                             Xl + r * 4224 + 64 + tid * 16);
            }
        }
        __syncthreads();

        // ---- compute: 9 taps; per tap 4 W-frags shared across 2 rows ----
        #pragma unroll
        for (int tap = 0; tap < 9; ++tap) {
            const int ti = tap / 3, tj = tap - ti * 3;
            bf16x8 af[4];
            #pragma unroll
            for (int mi = 0; mi < 4; ++mi) {
                const int o = mi * 16 + l15;
                int byte = (tap << 12) + (o << 6) + (hi << 4);
                byte ^= ((o & 6) << 3);
                af[mi] = *(const bf16x8*)(Wl + byte);
            }
            bf16x8 bg[2][4];
            #pragma unroll
            for (int rr = 0; rr < 2; ++rr) {
                const int row = 2 * wv + rr + ti;
                #pragma unroll
                for (int ni = 0; ni < 4; ++ni) {
                    const int col = ni * 16 + l15 + tj;
                    int byte = (((row * 66 + col) << 5) + (hi << 3)) << 1;
                    byte ^= ((col & 6) << 3);
                    bg[rr][ni] = *(const bf16x8*)(Xl + byte);
                }
            }
            __builtin_amdgcn_s_setprio(1);
            #pragma unroll
            for (int rr = 0; rr < 2; ++rr)
                #pragma unroll
                for (int mi = 0; mi < 4; ++mi)
                    #pragma unroll
                    for (int ni = 0; ni < 4; ++ni)
                        acc[rr][mi][ni] = __builtin_amdgcn_mfma_f32_16x16x32_bf16(
                            af[mi], bg[rr][ni], acc[rr][mi][ni], 0, 0, 0);
            __builtin_amdgcn_s_setprio(0);
        }
        if (cc != NCHUNK - 1) __syncthreads();
    }

    // ---- epilogue: *G, +bias, lrelu*gain, clamp, store interior + borders ----
    {
        const int obase = ot * 64;
        #pragma unroll
        for (int rr = 0; rr < 2; ++rr) {
            const int orow = h0 + 2 * wv + rr + 1;
            #pragma unroll
            for (int mi = 0; mi < 4; ++mi) {
                #pragma unroll
                for (int r = 0; r < 4; ++r) {
                    const int o = obase + mi * 16 + hi * 4 + r;
                    const float gg = g[b * COUT_ + o];
                    const float bb = bias[o];
                    float* op = out + ((size_t)(b * COUT_ + o) * 66 + orow) * 66;
                    #pragma unroll
                    for (int ni = 0; ni < 4; ++ni) {
                        float v = acc[rr][mi][ni][r] * gg + bb;
                        v = (v >= 0.f ? v : v * 0.2f) * GAIN_;
                        v = fminf(fmaxf(v, -CLAMP_), CLAMP_);
                        op[ni * 16 + l15 + 1] = v;
                    }
                    if (l15 == 0)  op[0]  = 0.f;
                    if (l15 == 15) op[65] = 0.f;
                }
            }
        }
        // top/bottom border rows for this block's 64 maps
        if (rt == 0 || rt == 7) {
            const int row = (rt == 0) ? 0 : 65;
            for (int i = tid; i < 64 * 66; i += 256) {
                const int o = obase + i / 66, col = i - (i / 66) * 66;
                out[((size_t)(b * COUT_ + o) * 66 + row) * 66 + col] = 0.f;
            }
        }
    }
}

// ---------------- launcher ----------------
extern "C" void kernel_launch(void* const* d_in, const int* in_sizes, int n_in,
                              void* d_out, int out_size, void* d_ws, size_t ws_size,
                              hipStream_t stream) {
    const float* x    = (const float*)d_in[0];
    const float* w    = (const float*)d_in[1];
    const float* aw   = (const float*)d_in[2];
    const float* ab   = (const float*)d_in[3];
    const float* cw   = (const float*)d_in[4];
    const float* bias = (const float*)d_in[5];
    const float* ema  = (const float*)d_in[6];
    float* out = (float*)d_out;

    float* wsf   = (float*)d_ws;
    float* s     = wsf;                 // 8192
    float* part  = wsf + 8192;          // 32
    float* alpha = wsf + 16512;         // 512
    float* Q     = wsf + 17024;         // 262144
    float* g     = wsf + 279168;        // 8192
    unsigned short* wb  = (unsigned short*)((char*)d_ws + 1179648);  // 4718592 B
    unsigned short* xbf = (unsigned short*)((char*)d_ws + 5898240);  // 67108864 B

    k_affine <<<32, 256, 0, stream>>>(w, aw, ab, s, part);
    k_wnorm  <<<512, 256, 0, stream>>>(cw, alpha, Q);
    k_g      <<<32, 256, 0, stream>>>(s, part, Q, alpha, ema, g);
    k_wprep2 <<<1152, 256, 0, stream>>>(cw, wb);
    k_xprep2 <<<2048, 256, 0, stream>>>(x, s, part, xbf);
    k_conv5  <<<1024, 256, 0, stream>>>(xbf, wb, g, bias, out);
}